// Round 1
// baseline (40.810 us; speedup 1.0000x reference)
//
#include <hip/hip_runtime.h>

// OHEM loss via per-row histogram select.
// 64 rows = 32 samples x 2 channels (0: region/char, 1: affinity).
// Per row: pos_cnt/pos_sum (label >= 0.1) + 2048-bin histogram of negative
// losses p^2 in [0,1). Each bin holds packed u64: (count << 40) | sum*2^20.
// top-k sum reconstructed from histogram (error ~1e-6 << 3.95e-2 threshold).

#define NB 2048
#define HSTRIDE 2056            // padded row stride in u64 (2048 bins + 1 pos slot)
#define NPIX 262144             // 512*512
#define C_CHUNKS 8
#define CHUNK (NPIX / C_CHUNKS) // 32768 elems per block
#define SCALE 1048576.0f        // 2^20 fixed point
#define INV_SCALE (1.0 / 1048576.0)

__global__ __launch_bounds__(1024)
void ohem_hist_kernel(const float* __restrict__ pred,
                      const float* __restrict__ region,
                      const float* __restrict__ affinity,
                      unsigned long long* __restrict__ g_hist)
{
    __shared__ unsigned long long h[NB + 1];
    const int row   = blockIdx.x / C_CHUNKS;   // 0..63
    const int chunk = blockIdx.x % C_CHUNKS;
    const int b = row & 31;
    const int c = row >> 5;                    // 0: region, 1: affinity
    const float* p = pred + (size_t)(b * 2 + c) * NPIX + (size_t)chunk * CHUNK;
    const float* s = (c == 0 ? region : affinity) + (size_t)b * NPIX + (size_t)chunk * CHUNK;

    for (int i = threadIdx.x; i <= NB; i += 1024) h[i] = 0;
    __syncthreads();

    const float4* p4 = (const float4*)p;
    const float4* s4 = (const float4*)s;
    #pragma unroll
    for (int it = 0; it < CHUNK / 4096; ++it) {  // 8 iterations, float4 each
        float4 pv = p4[it * 1024 + threadIdx.x];
        float4 sv = s4[it * 1024 + threadIdx.x];
        float pp[4]  = {pv.x, pv.y, pv.z, pv.w};
        float ssv[4] = {sv.x, sv.y, sv.z, sv.w};
        #pragma unroll
        for (int j = 0; j < 4; ++j) {
            float d = pp[j] - ssv[j];
            float x = d * d;                      // pre_loss, in [0,1]
            int bin;
            if (ssv[j] >= 0.1f) {
                bin = NB;                         // positive slot
            } else {
                bin = (int)(x * (float)NB);       // x < 1 for negatives (p^2, p<1)
                if (bin > NB - 1) bin = NB - 1;
            }
            unsigned long long packed =
                (1ULL << 40) | (unsigned long long)(x * SCALE + 0.5f);
            atomicAdd(&h[bin], packed);           // deterministic integer atomic
        }
    }
    __syncthreads();

    unsigned long long* gh = g_hist + (size_t)row * HSTRIDE;
    for (int i = threadIdx.x; i <= NB; i += 1024) {
        unsigned long long v = h[i];
        if (v) atomicAdd(&gh[i], v);
    }
}

__global__ __launch_bounds__(64)
void ohem_select_kernel(const unsigned long long* __restrict__ g_hist,
                        float* __restrict__ row_result)
{
    const int row = blockIdx.x;
    const unsigned long long* gh = g_hist + (size_t)row * HSTRIDE;
    const int t = threadIdx.x;   // single wave of 64
    const unsigned long long MASK = (1ULL << 40) - 1;

    // Each lane owns 32 consecutive bins counted FROM THE TOP.
    unsigned long long c_t = 0, s_t = 0;
    for (int j = 0; j < 32; ++j) {
        int bin = NB - 1 - (t * 32 + j);
        unsigned long long v = gh[bin];
        c_t += v >> 40;
        s_t += v & MASK;
    }
    // Inclusive scan across the wave (64-bit shuffles).
    unsigned long long ic = c_t, isum = s_t;
    for (int off = 1; off < 64; off <<= 1) {
        unsigned long long uc = __shfl_up(ic, off);
        unsigned long long us = __shfl_up(isum, off);
        if (t >= off) { ic += uc; isum += us; }
    }
    unsigned long long pre_c = ic - c_t;     // exclusive prefix (from top)
    unsigned long long pre_s = isum - s_t;

    unsigned long long pospack = gh[NB];
    unsigned long long pc = pospack >> 40;
    double psum = (double)(pospack & MASK) * INV_SCALE;
    long long negc = (long long)NPIX - (long long)pc;
    long long k;
    if (pc > 0) { k = 3LL * (long long)pc; if (k > negc) k = negc; }
    else        { k = 500; }                  // top-500-mean fallback path

    if (pc > 0 && k == 0) {                   // all pixels positive: nega = -1
        if (t == 0) row_result[row] = (float)(psum / (double)pc - 1.0);
        return;
    }

    // Exactly one lane contains the k-th value crossing.
    if ((long long)pre_c < k && k <= (long long)(pre_c + c_t)) {
        unsigned long long cum = pre_c, cums = pre_s;
        double nega = 0.0;
        for (int j = 0; j < 32; ++j) {
            int bin = NB - 1 - (t * 32 + j);
            unsigned long long v = gh[bin];
            unsigned long long cb = v >> 40, sb = v & MASK;
            if ((long long)(cum + cb) >= k) {
                unsigned long long need = (unsigned long long)k - cum;
                double avg = cb ? (double)sb / (double)cb : 0.0;
                nega = ((double)cums + (double)need * avg) * INV_SCALE / (double)k;
                break;
            }
            cum += cb; cums += sb;
        }
        double posi = (pc > 0) ? psum / (double)pc : 0.0;
        row_result[row] = (float)(posi + nega);
    }
}

__global__ void final_reduce_kernel(const float* __restrict__ row_result,
                                    float* __restrict__ out)
{
    float v = row_result[threadIdx.x];   // 64 lanes = 64 rows
    #pragma unroll
    for (int off = 32; off > 0; off >>= 1) v += __shfl_down(v, off);
    if (threadIdx.x == 0) out[0] = v * (1.0f / 32.0f);
}

extern "C" void kernel_launch(void* const* d_in, const int* in_sizes, int n_in,
                              void* d_out, int out_size, void* d_ws, size_t ws_size,
                              hipStream_t stream)
{
    const float* pred     = (const float*)d_in[0];
    const float* region   = (const float*)d_in[1];
    const float* affinity = (const float*)d_in[2];
    float* out = (float*)d_out;

    unsigned long long* g_hist = (unsigned long long*)d_ws;
    const size_t hist_bytes = (size_t)64 * HSTRIDE * sizeof(unsigned long long);
    float* row_result = (float*)((char*)d_ws + hist_bytes);

    hipMemsetAsync(d_ws, 0, hist_bytes + 64 * sizeof(float), stream);
    ohem_hist_kernel<<<64 * C_CHUNKS, 1024, 0, stream>>>(pred, region, affinity, g_hist);
    ohem_select_kernel<<<64, 64, 0, stream>>>(g_hist, row_result);
    final_reduce_kernel<<<1, 64, 0, stream>>>(row_result, out);
}